// Round 19
// baseline (615.208 us; speedup 1.0000x reference)
//
#include <hip/hip_runtime.h>
#include <math.h>

#define D_MODEL 512
#define D_FF    2048
#define N_EXP   8
#define N_TOK   8192
#define BM      64
#define BF      64

typedef _Float16 half8 __attribute__((ext_vector_type(8)));
typedef float    f32x4 __attribute__((ext_vector_type(4)));

__device__ __forceinline__ void gload_lds16(const void* g, void* lds) {
  __builtin_amdgcn_global_load_lds(
      (const __attribute__((address_space(1))) unsigned int*)g,
      (__attribute__((address_space(3))) unsigned int*)lds, 16, 0, 0);
}

// ---------------- x -> fp16 ----------------
__global__ void cvt_x_kernel(const float* __restrict__ x, _Float16* __restrict__ xb) {
  int i = blockIdx.x * blockDim.x + threadIdx.x;   // 8 elems per thread
  const float4* xp = (const float4*)x + (size_t)i * 2;
  float4 v0 = xp[0], v1 = xp[1];
  half8 o;
  o[0] = (_Float16)v0.x; o[1] = (_Float16)v0.y; o[2] = (_Float16)v0.z; o[3] = (_Float16)v0.w;
  o[4] = (_Float16)v1.x; o[5] = (_Float16)v1.y; o[6] = (_Float16)v1.z; o[7] = (_Float16)v1.w;
  ((half8*)xb)[i] = o;
}

// ---------------- [E][R][C] f32 -> [E][C][R] f16 ----------------
__global__ void transpose_cvt_kernel(const float* __restrict__ in, _Float16* __restrict__ out,
                                     int R, int C) {
  __shared__ float t[32][33];
  int e = blockIdx.z, rb = blockIdx.y, cb = blockIdx.x;
  int tx = threadIdx.x & 31, ty = threadIdx.x >> 5;
  const float* src = in + ((size_t)e * R + rb * 32) * C + cb * 32;
#pragma unroll
  for (int i = 0; i < 32; i += 8) t[ty + i][tx] = src[(size_t)(ty + i) * C + tx];
  __syncthreads();
  _Float16* dst = out + ((size_t)e * C + cb * 32) * R + rb * 32;
#pragma unroll
  for (int i = 0; i < 32; i += 8) dst[(size_t)(ty + i) * R + tx] = (_Float16)t[tx][ty + i];
}

// ---------------- router: softmax(x @ wr + br) ----------------
__global__ void router_kernel(const float* __restrict__ x, const float* __restrict__ wr,
                              const float* __restrict__ br, float* __restrict__ route) {
  int t = (blockIdx.x * blockDim.x + threadIdx.x) >> 6;   // one wave per token
  int lane = threadIdx.x & 63;
  const float4* xp = (const float4*)(x + (size_t)t * D_MODEL) + lane * 2;
  float4 xv0 = xp[0], xv1 = xp[1];
  float xv[8] = {xv0.x, xv0.y, xv0.z, xv0.w, xv1.x, xv1.y, xv1.z, xv1.w};
  float acc[8] = {0, 0, 0, 0, 0, 0, 0, 0};
  int d0 = lane * 8;
#pragma unroll
  for (int i = 0; i < 8; ++i) {
    const float4* wp = (const float4*)(wr + (size_t)(d0 + i) * N_EXP);
    float4 w0 = wp[0], w1v = wp[1];
    acc[0] += xv[i] * w0.x;  acc[1] += xv[i] * w0.y;
    acc[2] += xv[i] * w0.z;  acc[3] += xv[i] * w0.w;
    acc[4] += xv[i] * w1v.x; acc[5] += xv[i] * w1v.y;
    acc[6] += xv[i] * w1v.z; acc[7] += xv[i] * w1v.w;
  }
#pragma unroll
  for (int off = 32; off > 0; off >>= 1)
#pragma unroll
    for (int e2 = 0; e2 < 8; ++e2) acc[e2] += __shfl_xor(acc[e2], off);
  float mx = -1e30f;
#pragma unroll
  for (int e2 = 0; e2 < 8; ++e2) { acc[e2] += br[e2]; mx = fmaxf(mx, acc[e2]); }
  float s = 0.f;
#pragma unroll
  for (int e2 = 0; e2 < 8; ++e2) { acc[e2] = expf(acc[e2] - mx); s += acc[e2]; }
  float inv = 1.f / s;
  if (lane < 8) route[(size_t)t * N_EXP + lane] = acc[lane] * inv;
}

// ---------------- staging: 32KB chunk-halves, 2 gload_lds per call ----------------
// chA[kh]: w1 K-half [64f][256k], row 512B = 32 x 16B groups; LDS group g holds
//          source k-group g ^ (f & 31)  (5-bit XOR involution, conflict-free).
// chB[dh]: w2 d-half [256d][64f], row 128B = 8 groups; group g holds source
//          f-group g ^ (d & 7).
__device__ __forceinline__ void stage_A_half(const _Float16* __restrict__ w1t, int e, int f0,
                                             int khalf, char* dst, int w, int l, int i0) {
#pragma unroll
  for (int i = i0; i < i0 + 2; ++i) {
    const int n  = i * 8 + w;                     // 0..31, 1KB per instr = 2 rows
    const int f  = 2 * n + (l >> 5);
    const int sp = (l & 31) ^ (f & 31);           // inverse of 5-bit read swizzle
    gload_lds16(w1t + ((size_t)e * D_FF + f0 + f) * D_MODEL + khalf * 256 + sp * 8,
                dst + n * 1024);
  }
}
__device__ __forceinline__ void stage_B_half(const _Float16* __restrict__ w2t, int e, int f0,
                                             int dh, char* dst, int w, int l, int i0) {
#pragma unroll
  for (int i = i0; i < i0 + 2; ++i) {
    const int n  = i * 8 + w;                     // 0..31, 1KB per instr = 8 rows
    const int d  = 8 * n + (l >> 3);
    const int sp = (l & 7) ^ (d & 7);
    gload_lds16(w2t + ((size_t)e * D_MODEL + dh * 256 + d) * D_FF + f0 + sp * 8,
                dst + n * 1024);
  }
}

// ---------------- fused MoE main: 8-phase counted-vmcnt, G1 K-split (m2xf2xk2) ----------------
// G1 wave grid: (mh1 = w&1, fh1 = (w>>1)&1, khg = w>>2). ALL waves active every
// phase (fixes r12's idle-wave K-split): khg reads chA[khg] only -> G1 B-reads
// 256 -> 128 per block-fc. K-half partials combined IN-PLACE in hs (f16,
// r12-validated): khg0 writes partials (P4a barrier), khg1 reads+adds+gelu+
// rewrites (P4b barrier). Stage plan: Bh1@P1-P2, Ah0n@c0, Ah1n@c1, Bh0n@c2.
// Waits: vmcnt(6)@P1 (chA both halves), vmcnt(4)@P4b (chB0), vmcnt(8)@c1 (chB1).
// All slot overwrites now HARD barrier-separated. 4 barriers/fc.
__global__ __launch_bounds__(512, 2)
void moe_main_kernel(const _Float16* __restrict__ xb, const _Float16* __restrict__ w1t,
                     const _Float16* __restrict__ w2t, const float* __restrict__ b1,
                     const float* __restrict__ b2, const float* __restrict__ route,
                     float* __restrict__ out) {
  __shared__ __align__(16) unsigned char chA[2][32768];   // w1 K-halves [64f][256k]
  __shared__ __align__(16) unsigned char chB[2][32768];   // w2 d-halves [256d][64f]
  __shared__ __align__(16) unsigned char hs[BM * 128];    // 8 KB [64m][64f] (partial->final)
  __shared__ _Float16 b1_lds[4 * D_FF];                   // 16 KB
  __shared__ float routes_lds[4][BM];                     // 1 KB

  const int tid = threadIdx.x;
  const int l   = tid & 63;
  const int w   = tid >> 6;
  const int eb  = 4 * blockIdx.y;
  const int m0  = blockIdx.x * BM;

  const int mh1 = w & 1;          // G1 m-half (32 rows: 2 mi frags)
  const int fh1 = (w >> 1) & 1;   // G1 f-half (32 cols: 2 j frags)
  const int khg = w >> 2;         // G1 K-half owner
  const int mh2 = w & 1;          // G2 m-half
  const int dq4 = w >> 1;         // G2 d-quad

  // stage b1 (4 experts, f16) + routes to LDS
#pragma unroll
  for (int i = 0; i < 16; ++i) {
    int idx = i * 512 + tid;
    b1_lds[idx] = (_Float16)b1[(size_t)(eb + (idx >> 11)) * D_FF + (idx & 2047)];
  }
  if (tid < 4 * BM)
    routes_lds[tid >> 6][tid & 63] = route[(size_t)(m0 + (tid & 63)) * N_EXP + eb + (tid >> 6)];
  asm volatile("s_waitcnt lgkmcnt(0)" ::: "memory");

  // x A-fragments: rows m0 + 32*mh1 + 16*mi + (l&15), this wave's K-half = 2x8 half8 (64 VGPR)
  half8 xfrag[2][8];
#pragma unroll
  for (int mi = 0; mi < 2; ++mi) {
    const _Float16* xrow = xb + (size_t)(m0 + 32 * mh1 + 16 * mi + (l & 15)) * D_MODEL
                              + khg * 256 + (l >> 4) * 8;
#pragma unroll
    for (int ks = 0; ks < 8; ++ks)
      xfrag[mi][ks] = *(const half8*)(xrow + ks * 32);
  }

  f32x4 acc[2][8];        // G2 accumulator — AGPR-resident
#pragma unroll
  for (int a = 0; a < 2; ++a)
#pragma unroll
    for (int b = 0; b < 8; ++b) acc[a][b] = (f32x4){0.f, 0.f, 0.f, 0.f};

  // prologue: Ah0, Ah1, Bh0 of (eb, fc0); Bh1(fc0) staged in P1-P2.
  stage_A_half(w1t, eb, 0, 0, (char*)chA[0], w, l, 0);
  stage_A_half(w1t, eb, 0, 0, (char*)chA[0], w, l, 2);
  stage_A_half(w1t, eb, 0, 1, (char*)chA[1], w, l, 0);
  stage_A_half(w1t, eb, 0, 1, (char*)chA[1], w, l, 2);
  stage_B_half(w2t, eb, 0, 0, (char*)chB[0], w, l, 0);
  stage_B_half(w2t, eb, 0, 0, (char*)chB[0], w, l, 2);
  __builtin_amdgcn_s_barrier();   // publish routes/b1 (lgkm drained above)

#pragma unroll 1
  for (int ei = 0; ei < 4; ++ei) {
    const int e = eb + ei;
#pragma unroll 1
    for (int fc = 0; fc < 32; ++fc) {
      const int f0 = fc * BF;
      int f0N = f0 + BF, eN = e;
      if (f0N == D_FF) { f0N = 0; eN = (ei < 3) ? e + 1 : eb; }   // tail wrap (harmless)

      f32x4 hacc[2][2];   // [mi][j] K-half partial
#pragma unroll
      for (int mi = 0; mi < 2; ++mi)
#pragma unroll
        for (int j = 0; j < 2; ++j) hacc[mi][j] = (f32x4){0.f, 0.f, 0.f, 0.f};

      // ======== P1..P4: GEMM1, each wave on its K-half; 8 MFMA/phase ========
#pragma unroll
      for (int p = 0; p < 4; ++p) {
        if (p == 0) {
          stage_B_half(w2t, e, f0, 1, (char*)chB[1], w, l, 0);
          asm volatile("s_waitcnt vmcnt(6)" ::: "memory");   // chA[0]+chA[1] landed
          __builtin_amdgcn_s_barrier();                      // P1: chA visible
        } else if (p == 1) {
          stage_B_half(w2t, e, f0, 1, (char*)chB[1], w, l, 2);
        }
        half8 bfr[2][2];
#pragma unroll
        for (int ks2 = 0; ks2 < 2; ++ks2)
#pragma unroll
          for (int j = 0; j < 2; ++j) {
            const int f  = 32 * fh1 + 16 * j + (l & 15);
            const int g  = (p * 2 + ks2) * 4 + (l >> 4);
            const int sw = (g ^ f) & 31;        // 5-bit XOR: conflict-free
            bfr[ks2][j] = *(const half8*)(chA[khg] + f * 512 + sw * 16);
          }
        asm volatile("s_waitcnt lgkmcnt(0)" ::: "memory");
        __builtin_amdgcn_s_setprio(1);
#pragma unroll
        for (int ks2 = 0; ks2 < 2; ++ks2)
#pragma unroll
          for (int j = 0; j < 2; ++j) {
            hacc[0][j] = __builtin_amdgcn_mfma_f32_16x16x32_f16(xfrag[0][p * 2 + ks2], bfr[ks2][j], hacc[0][j], 0, 0, 0);
            hacc[1][j] = __builtin_amdgcn_mfma_f32_16x16x32_f16(xfrag[1][p * 2 + ks2], bfr[ks2][j], hacc[1][j], 0, 0, 0);
          }
        __builtin_amdgcn_s_setprio(0);
      }

      // ======== K-half combine (in-place in hs, f16) ========
      if (khg == 0) {   // write K-half-0 partials
#pragma unroll
        for (int mi = 0; mi < 2; ++mi)
#pragma unroll
          for (int j = 0; j < 2; ++j)
#pragma unroll
            for (int r = 0; r < 4; ++r) {
              const int m  = 32 * mh1 + 16 * mi + (l >> 4) * 4 + r;
              const int fl = 32 * fh1 + 16 * j + (l & 15);
              const int sh = (fl >> 3) ^ ((m ^ (m >> 1)) & 7);
              *(_Float16*)(hs + m * 128 + sh * 16 + (fl & 7) * 2) = (_Float16)hacc[mi][j][r];
            }
        asm volatile("s_waitcnt lgkmcnt(0)" ::: "memory");
      }
      __builtin_amdgcn_s_barrier();                          // P4a: partials visible
      if (khg == 1) {   // combine + bias + tanh-gelu + route-scale
        float b1v[2];
#pragma unroll
        for (int j = 0; j < 2; ++j)
          b1v[j] = (float)b1_lds[ei * D_FF + f0 + 32 * fh1 + 16 * j + (l & 15)];
#pragma unroll
        for (int mi = 0; mi < 2; ++mi)
#pragma unroll
          for (int j = 0; j < 2; ++j)
#pragma unroll
            for (int r = 0; r < 4; ++r) {
              const int m  = 32 * mh1 + 16 * mi + (l >> 4) * 4 + r;
              const int fl = 32 * fh1 + 16 * j + (l & 15);
              const int sh = (fl >> 3) ^ ((m ^ (m >> 1)) & 7);
              _Float16* ptr = (_Float16*)(hs + m * 128 + sh * 16 + (fl & 7) * 2);
              float v  = (float)*ptr + hacc[mi][j][r] + b1v[j];
              float u  = v * (1.5957691f + 0.0713548f * v * v);
              float E  = __expf(u);
              float gl = v * E / (E + 1.0f);
              gl *= routes_lds[ei][m];
              *ptr = (_Float16)gl;
            }
        asm volatile("s_waitcnt lgkmcnt(0)" ::: "memory");
      }
      asm volatile("s_waitcnt vmcnt(4)" ::: "memory");       // chB[0] landed
      __builtin_amdgcn_s_barrier();                          // P4b: hs final + chB[0] visible

      // ======== P5..P8 (c): GEMM2, 8 MFMA each ========
      half8 a2c[2][2];   // [kh][mi2] — loaded at c=0,1; reused at c=2,3
#pragma unroll
      for (int c = 0; c < 4; ++c) {
        const int h  = c >> 1;
        const int kh = c & 1;
        if (c == 0) {
          stage_A_half(w1t, eN, f0N, 0, (char*)chA[0], w, l, 0);
          stage_A_half(w1t, eN, f0N, 0, (char*)chA[0], w, l, 2);
        } else if (c == 1) {
          stage_A_half(w1t, eN, f0N, 1, (char*)chA[1], w, l, 0);
          stage_A_half(w1t, eN, f0N, 1, (char*)chA[1], w, l, 2);
          asm volatile("s_waitcnt vmcnt(8)" ::: "memory");   // chB[1] landed
          __builtin_amdgcn_s_barrier();                      // c1: chB[1] visible
        } else if (c == 2) {
          stage_B_half(w2t, eN, f0N, 0, (char*)chB[0], w, l, 0);
          stage_B_half(w2t, eN, f0N, 0, (char*)chB[0], w, l, 2);
        }
        if (h == 0) {
#pragma unroll
          for (int mi2 = 0; mi2 < 2; ++mi2) {
            const int mr = 32 * mh2 + 16 * mi2 + (l & 15);
            const int sh = (kh * 4 + (l >> 4)) ^ ((mr ^ (mr >> 1)) & 7);
            a2c[kh][mi2] = *(const half8*)(hs + mr * 128 + sh * 16);
          }
        }
        half8 b2f[4];
#pragma unroll
        for (int jn = 0; jn < 4; ++jn) {
          const int row = dq4 * 64 + jn * 16 + (l & 15);
          const int sw  = (kh * 4 + (l >> 4)) ^ (row & 7);
          b2f[jn] = *(const half8*)(chB[h] + row * 128 + sw * 16);
        }
        asm volatile("s_waitcnt lgkmcnt(0)" ::: "memory");
        __builtin_amdgcn_s_setprio(1);
#pragma unroll
        for (int jn = 0; jn < 4; ++jn) {
          acc[0][h * 4 + jn] = __builtin_amdgcn_mfma_f32_16x16x32_f16(a2c[kh][0], b2f[jn], acc[0][h * 4 + jn], 0, 0, 0);
          acc[1][h * 4 + jn] = __builtin_amdgcn_mfma_f32_16x16x32_f16(a2c[kh][1], b2f[jn], acc[1][h * 4 + jn], 0, 0, 0);
        }
        __builtin_amdgcn_s_setprio(0);
      }
    }
  }

  asm volatile("s_waitcnt vmcnt(0)" ::: "memory");   // drain tail prefetches

  // ---- epilogue: += sum_e route*b2, then 2-way atomic accumulate ----
#pragma unroll
  for (int h = 0; h < 2; ++h)
#pragma unroll
    for (int jn = 0; jn < 4; ++jn) {
      const int dcol = h * 256 + dq4 * 64 + jn * 16 + (l & 15);
      float b2v[4];
#pragma unroll
      for (int ei = 0; ei < 4; ++ei) b2v[ei] = b2[(size_t)(eb + ei) * D_MODEL + dcol];
#pragma unroll
      for (int mi2 = 0; mi2 < 2; ++mi2)
#pragma unroll
        for (int r = 0; r < 4; ++r) {
          const int m = 32 * mh2 + 16 * mi2 + (l >> 4) * 4 + r;
          float add = 0.f;
#pragma unroll
          for (int ei = 0; ei < 4; ++ei) add += routes_lds[ei][m] * b2v[ei];
          unsafeAtomicAdd(out + (size_t)(m0 + m) * D_MODEL + dcol, acc[mi2][h * 4 + jn][r] + add);
        }
    }
}

extern "C" void kernel_launch(void* const* d_in, const int* in_sizes, int n_in,
                              void* d_out, int out_size, void* d_ws, size_t ws_size,
                              hipStream_t stream) {
  (void)in_sizes; (void)n_in; (void)out_size; (void)ws_size;
  const float* x  = (const float*)d_in[0];
  const float* w1 = (const float*)d_in[1];
  const float* b1 = (const float*)d_in[2];
  const float* w2 = (const float*)d_in[3];
  const float* b2 = (const float*)d_in[4];
  const float* wr = (const float*)d_in[5];
  const float* br = (const float*)d_in[6];
  float* out   = (float*)d_out;
  float* route = out + (size_t)N_TOK * D_MODEL;   // output 1 lives in d_out tail

  char* ws = (char*)d_ws;
  _Float16* xb  = (_Float16*)ws;                                           // 8 MiB
  _Float16* w1t = (_Float16*)(ws + (size_t)N_TOK * D_MODEL * 2);           // +16 MiB  [E][F][D]
  _Float16* w2t = (_Float16*)(ws + (size_t)N_TOK * D_MODEL * 2
                                 + (size_t)N_EXP * D_FF * D_MODEL * 2);    // +16 MiB  [E][D][F]

  hipMemsetAsync(out, 0, (size_t)N_TOK * D_MODEL * sizeof(float), stream);
  cvt_x_kernel<<<(N_TOK * D_MODEL / 8) / 256, 256, 0, stream>>>(x, xb);
  transpose_cvt_kernel<<<dim3(D_FF / 32, D_MODEL / 32, N_EXP), 256, 0, stream>>>(w1, w1t, D_MODEL, D_FF);
  transpose_cvt_kernel<<<dim3(D_MODEL / 32, D_FF / 32, N_EXP), 256, 0, stream>>>(w2, w2t, D_FF, D_MODEL);
  router_kernel<<<N_TOK / 4, 256, 0, stream>>>(x, wr, br, route);
  moe_main_kernel<<<dim3(N_TOK / BM, 2), 512, 0, stream>>>(xb, w1t, w2t, b1, b2, route, out);
}

// Round 20
// 413.525 us; speedup vs baseline: 1.4877x; 1.4877x over previous
//
#include <hip/hip_runtime.h>
#include <math.h>

#define D_MODEL 512
#define D_FF    2048
#define N_EXP   8
#define N_TOK   8192
#define BM      64
#define BF      64

typedef _Float16 half8 __attribute__((ext_vector_type(8)));
typedef float    f32x4 __attribute__((ext_vector_type(4)));

__device__ __forceinline__ void gload_lds16(const void* g, void* lds) {
  __builtin_amdgcn_global_load_lds(
      (const __attribute__((address_space(1))) unsigned int*)g,
      (__attribute__((address_space(3))) unsigned int*)lds, 16, 0, 0);
}

// ---------------- x -> fp16 ----------------
__global__ void cvt_x_kernel(const float* __restrict__ x, _Float16* __restrict__ xb) {
  int i = blockIdx.x * blockDim.x + threadIdx.x;   // 8 elems per thread
  const float4* xp = (const float4*)x + (size_t)i * 2;
  float4 v0 = xp[0], v1 = xp[1];
  half8 o;
  o[0] = (_Float16)v0.x; o[1] = (_Float16)v0.y; o[2] = (_Float16)v0.z; o[3] = (_Float16)v0.w;
  o[4] = (_Float16)v1.x; o[5] = (_Float16)v1.y; o[6] = (_Float16)v1.z; o[7] = (_Float16)v1.w;
  ((half8*)xb)[i] = o;
}

// ---------------- [E][R][C] f32 -> [E][C][R] f16 ----------------
__global__ void transpose_cvt_kernel(const float* __restrict__ in, _Float16* __restrict__ out,
                                     int R, int C) {
  __shared__ float t[32][33];
  int e = blockIdx.z, rb = blockIdx.y, cb = blockIdx.x;
  int tx = threadIdx.x & 31, ty = threadIdx.x >> 5;
  const float* src = in + ((size_t)e * R + rb * 32) * C + cb * 32;
#pragma unroll
  for (int i = 0; i < 32; i += 8) t[ty + i][tx] = src[(size_t)(ty + i) * C + tx];
  __syncthreads();
  _Float16* dst = out + ((size_t)e * C + cb * 32) * R + rb * 32;
#pragma unroll
  for (int i = 0; i < 32; i += 8) dst[(size_t)(ty + i) * R + tx] = (_Float16)t[tx][ty + i];
}

// ---------------- router: softmax(x @ wr + br) ----------------
__global__ void router_kernel(const float* __restrict__ x, const float* __restrict__ wr,
                              const float* __restrict__ br, float* __restrict__ route) {
  int t = (blockIdx.x * blockDim.x + threadIdx.x) >> 6;   // one wave per token
  int lane = threadIdx.x & 63;
  const float4* xp = (const float4*)(x + (size_t)t * D_MODEL) + lane * 2;
  float4 xv0 = xp[0], xv1 = xp[1];
  float xv[8] = {xv0.x, xv0.y, xv0.z, xv0.w, xv1.x, xv1.y, xv1.z, xv1.w};
  float acc[8] = {0, 0, 0, 0, 0, 0, 0, 0};
  int d0 = lane * 8;
#pragma unroll
  for (int i = 0; i < 8; ++i) {
    const float4* wp = (const float4*)(wr + (size_t)(d0 + i) * N_EXP);
    float4 w0 = wp[0], w1v = wp[1];
    acc[0] += xv[i] * w0.x;  acc[1] += xv[i] * w0.y;
    acc[2] += xv[i] * w0.z;  acc[3] += xv[i] * w0.w;
    acc[4] += xv[i] * w1v.x; acc[5] += xv[i] * w1v.y;
    acc[6] += xv[i] * w1v.z; acc[7] += xv[i] * w1v.w;
  }
#pragma unroll
  for (int off = 32; off > 0; off >>= 1)
#pragma unroll
    for (int e2 = 0; e2 < 8; ++e2) acc[e2] += __shfl_xor(acc[e2], off);
  float mx = -1e30f;
#pragma unroll
  for (int e2 = 0; e2 < 8; ++e2) { acc[e2] += br[e2]; mx = fmaxf(mx, acc[e2]); }
  float s = 0.f;
#pragma unroll
  for (int e2 = 0; e2 < 8; ++e2) { acc[e2] = expf(acc[e2] - mx); s += acc[e2]; }
  float inv = 1.f / s;
  if (lane < 8) route[(size_t)t * N_EXP + lane] = acc[lane] * inv;
}

// ---------------- staging: 32KB chunk-halves, 2 gload_lds per call ----------------
// chA[kh]: w1 K-half [64f][256k], row 512B = 32 x 16B groups; LDS group g holds
//          source k-group g ^ (f & 31)  (5-bit XOR involution — r12/r13-proven:
//          ZERO counted conflicts).
// chB[dh]: w2 d-half [256d][64f], row 128B = 8 groups; group g holds source
//          f-group g ^ (d & 7).   (measured conflict-free)
__device__ __forceinline__ void stage_A_half(const _Float16* __restrict__ w1t, int e, int f0,
                                             int khalf, char* dst, int w, int l, int i0) {
#pragma unroll
  for (int i = i0; i < i0 + 2; ++i) {
    const int n  = i * 8 + w;                     // 0..31, 1KB per instr = 2 rows
    const int f  = 2 * n + (l >> 5);
    const int sp = (l & 31) ^ (f & 31);           // inverse of 5-bit read swizzle
    gload_lds16(w1t + ((size_t)e * D_FF + f0 + f) * D_MODEL + khalf * 256 + sp * 8,
                dst + n * 1024);
  }
}
__device__ __forceinline__ void stage_B_half(const _Float16* __restrict__ w2t, int e, int f0,
                                             int dh, char* dst, int w, int l, int i0) {
#pragma unroll
  for (int i = i0; i < i0 + 2; ++i) {
    const int n  = i * 8 + w;                     // 0..31, 1KB per instr = 8 rows
    const int d  = 8 * n + (l >> 3);
    const int sp = (l & 7) ^ (d & 7);
    gload_lds16(w2t + ((size_t)e * D_MODEL + dh * 256 + d) * D_FF + f0 + sp * 8,
                dst + n * 1024);
  }
}

// ---------------- fused MoE main: 8-phase counted-vmcnt, 5 barriers/fc ----------------
// r18 BEST CONFIG (403us), resubmitted after r19's K-split regression (608us:
// the K-half combine is a serialized half-idle scalar-LDS phase costing more
// than the saved B-reads — K-split measured negative twice, r12 & r19).
// Barriers kept: P2 (chA[1] vis), P4-leading (chB[0] vis), P4-trailing
// (hs publish), P6 (chB[1] vis), P8 (next chA[0] vis).
__global__ __launch_bounds__(512, 2)
void moe_main_kernel(const _Float16* __restrict__ xb, const _Float16* __restrict__ w1t,
                     const _Float16* __restrict__ w2t, const float* __restrict__ b1,
                     const float* __restrict__ b2, const float* __restrict__ route,
                     float* __restrict__ out) {
  __shared__ __align__(16) unsigned char chA[2][32768];   // w1 K-halves [64f][256k]
  __shared__ __align__(16) unsigned char chB[2][32768];   // w2 d-halves [256d][64f]
  __shared__ __align__(16) unsigned char hs[BM * 128];    // 8 KB [64m][64f]
  __shared__ _Float16 b1_lds[4 * D_FF];                   // 16 KB
  __shared__ float routes_lds[4][BM];                     // 1 KB

  const int tid = threadIdx.x;
  const int l   = tid & 63;
  const int w   = tid >> 6;
  const int eb  = 4 * blockIdx.y;
  const int m0  = blockIdx.x * BM;

  const int mq  = w & 3;                   // G1 m-quarter (16 rows)
  const int fh  = w >> 2;                  // G1 f-half (32 cols)
  const int mh2 = w & 1;                   // G2 m-half (32 rows)
  const int dq4 = w >> 1;                  // G2 d-quad (64 cols per d-half)

  // stage b1 (4 experts, f16) + routes to LDS
#pragma unroll
  for (int i = 0; i < 16; ++i) {
    int idx = i * 512 + tid;
    b1_lds[idx] = (_Float16)b1[(size_t)(eb + (idx >> 11)) * D_FF + (idx & 2047)];
  }
  if (tid < 4 * BM)
    routes_lds[tid >> 6][tid & 63] = route[(size_t)(m0 + (tid & 63)) * N_EXP + eb + (tid >> 6)];
  asm volatile("s_waitcnt lgkmcnt(0)" ::: "memory");

  // x A-fragments: rows m0 + 16*mq + (l&15), K=512 -> 16 x half8 = 64 VGPR
  half8 xfrag[16];
  {
    const _Float16* xrow = xb + (size_t)(m0 + 16 * mq + (l & 15)) * D_MODEL + (l >> 4) * 8;
#pragma unroll
    for (int ks = 0; ks < 16; ++ks)
      xfrag[ks] = *(const half8*)(xrow + ks * 32);
  }

  f32x4 acc[2][8];        // [mi2][h*4+jn] — AGPR-resident
#pragma unroll
  for (int a = 0; a < 2; ++a)
#pragma unroll
    for (int b = 0; b < 8; ++b) acc[a][b] = (f32x4){0.f, 0.f, 0.f, 0.f};

  // prologue: Ah0, Ah1, Bh0 of (eb, fc0); Bh1(fc0) staged in P1-2.
  stage_A_half(w1t, eb, 0, 0, (char*)chA[0], w, l, 0);
  stage_A_half(w1t, eb, 0, 0, (char*)chA[0], w, l, 2);
  stage_A_half(w1t, eb, 0, 1, (char*)chA[1], w, l, 0);
  stage_A_half(w1t, eb, 0, 1, (char*)chA[1], w, l, 2);
  stage_B_half(w2t, eb, 0, 0, (char*)chB[0], w, l, 0);
  stage_B_half(w2t, eb, 0, 0, (char*)chB[0], w, l, 2);
  asm volatile("s_waitcnt vmcnt(8)" ::: "memory");   // Ah0 landed
  __builtin_amdgcn_s_barrier();

#pragma unroll 1
  for (int ei = 0; ei < 4; ++ei) {
    const int e = eb + ei;
#pragma unroll 1
    for (int fc = 0; fc < 32; ++fc) {
      const int f0 = fc * BF;
      int f0N = f0 + BF, eN = e;
      if (f0N == D_FF) { f0N = 0; eN = (ei < 3) ? e + 1 : eb; }   // tail wrap (harmless)

      float b1v[2];
#pragma unroll
      for (int j = 0; j < 2; ++j)
        b1v[j] = (float)b1_lds[ei * D_FF + f0 + 32 * fh + 16 * j + (l & 15)];

      f32x4 hacc[2];
      hacc[0] = (f32x4){0.f, 0.f, 0.f, 0.f};
      hacc[1] = (f32x4){0.f, 0.f, 0.f, 0.f};

      // ======== P1..P4: GEMM1 (kq = K-quarter), 8 MFMA each ========
#pragma unroll
      for (int kq = 0; kq < 4; ++kq) {
        const unsigned char* cA = chA[kq >> 1];
        const int q = kq & 1;
        half8 bfr[4][2];
#pragma unroll
        for (int t = 0; t < 4; ++t)
#pragma unroll
          for (int j = 0; j < 2; ++j) {
            const int f  = 32 * fh + 16 * j + (l & 15);
            const int g  = q * 16 + t * 4 + (l >> 4);
            const int sw = (g ^ f) & 31;          // 5-bit XOR: conflict-free
            bfr[t][j] = *(const half8*)(cA + f * 512 + sw * 16);
          }
        if      (kq == 0) stage_B_half(w2t, e,  f0,  1, (char*)chB[1], w, l, 0);
        else if (kq == 1) stage_B_half(w2t, e,  f0,  1, (char*)chB[1], w, l, 2);
        else if (kq == 2) stage_A_half(w1t, eN, f0N, 0, (char*)chA[0], w, l, 0);
        else              stage_A_half(w1t, eN, f0N, 0, (char*)chA[0], w, l, 2);
        if (kq & 1) {
          asm volatile("s_waitcnt vmcnt(8)" ::: "memory");
          __builtin_amdgcn_s_barrier();            // P2/P4 leading: chunk visibility
        }
        asm volatile("s_waitcnt lgkmcnt(0)" ::: "memory");
        __builtin_amdgcn_s_setprio(1);
#pragma unroll
        for (int t = 0; t < 4; ++t) {
          hacc[0] = __builtin_amdgcn_mfma_f32_16x16x32_f16(xfrag[kq * 4 + t], bfr[t][0], hacc[0], 0, 0, 0);
          hacc[1] = __builtin_amdgcn_mfma_f32_16x16x32_f16(xfrag[kq * 4 + t], bfr[t][1], hacc[1], 0, 0, 0);
        }
        __builtin_amdgcn_s_setprio(0);
        if (kq == 3) {
          // bias + tanh-gelu + route-scale -> hs (16 rows x 32 cols per wave)
#pragma unroll
          for (int j = 0; j < 2; ++j) {
#pragma unroll
            for (int r = 0; r < 4; ++r) {
              const int m      = 16 * mq + (l >> 4) * 4 + r;
              const int flocal = 32 * fh + 16 * j + (l & 15);
              float v  = hacc[j][r] + b1v[j];
              float u  = v * (1.5957691f + 0.0713548f * v * v);
              float E  = __expf(u);
              float gl = v * E / (E + 1.0f);
              gl *= routes_lds[ei][m];
              const int sh = (flocal >> 3) ^ ((m ^ (m >> 1)) & 7);
              *(_Float16*)(hs + m * 128 + sh * 16 + (flocal & 7) * 2) = (_Float16)gl;
            }
          }
          asm volatile("s_waitcnt lgkmcnt(0)" ::: "memory");
          __builtin_amdgcn_s_barrier();            // P4 trailing: hs publish
        }
      }

      // ======== P5..P8: GEMM2 (c: h = c>>1 d-half, kh = c&1), 8 MFMA each ========
      half8 a2c[2][2];   // [kh][mi2] — loaded at c=0,1; reused at c=2,3
#pragma unroll
      for (int c = 0; c < 4; ++c) {
        const int h  = c >> 1;
        const int kh = c & 1;
        if (h == 0) {
#pragma unroll
          for (int mi2 = 0; mi2 < 2; ++mi2) {
            const int mr = 32 * mh2 + 16 * mi2 + (l & 15);
            const int sh = (kh * 4 + (l >> 4)) ^ ((mr ^ (mr >> 1)) & 7);
            a2c[kh][mi2] = *(const half8*)(hs + mr * 128 + sh * 16);
          }
        }
        half8 b2f[4];
#pragma unroll
        for (int jn = 0; jn < 4; ++jn) {
          const int row = dq4 * 64 + jn * 16 + (l & 15);
          const int sw  = (kh * 4 + (l >> 4)) ^ (row & 7);
          b2f[jn] = *(const half8*)(chB[h] + row * 128 + sw * 16);
        }
        if      (c == 0) stage_A_half(w1t, eN, f0N, 1, (char*)chA[1], w, l, 0);
        else if (c == 1) stage_A_half(w1t, eN, f0N, 1, (char*)chA[1], w, l, 2);
        else if (c == 2) stage_B_half(w2t, eN, f0N, 0, (char*)chB[0], w, l, 0);
        else             stage_B_half(w2t, eN, f0N, 0, (char*)chB[0], w, l, 2);
        if (c & 1) {
          asm volatile("s_waitcnt vmcnt(8)" ::: "memory");
          __builtin_amdgcn_s_barrier();            // P6/P8 leading: chunk visibility
        }
        asm volatile("s_waitcnt lgkmcnt(0)" ::: "memory");
        __builtin_amdgcn_s_setprio(1);
#pragma unroll
        for (int jn = 0; jn < 4; ++jn) {
          acc[0][h * 4 + jn] = __builtin_amdgcn_mfma_f32_16x16x32_f16(a2c[kh][0], b2f[jn], acc[0][h * 4 + jn], 0, 0, 0);
          acc[1][h * 4 + jn] = __builtin_amdgcn_mfma_f32_16x16x32_f16(a2c[kh][1], b2f[jn], acc[1][h * 4 + jn], 0, 0, 0);
        }
        __builtin_amdgcn_s_setprio(0);
      }
    }
  }

  asm volatile("s_waitcnt vmcnt(0)" ::: "memory");   // drain tail prefetches

  // ---- epilogue: += sum_e route*b2, then 2-way atomic accumulate ----
#pragma unroll
  for (int h = 0; h < 2; ++h)
#pragma unroll
    for (int jn = 0; jn < 4; ++jn) {
      const int dcol = h * 256 + dq4 * 64 + jn * 16 + (l & 15);
      float b2v[4];
#pragma unroll
      for (int ei = 0; ei < 4; ++ei) b2v[ei] = b2[(size_t)(eb + ei) * D_MODEL + dcol];
#pragma unroll
      for (int mi2 = 0; mi2 < 2; ++mi2)
#pragma unroll
        for (int r = 0; r < 4; ++r) {
          const int m = 32 * mh2 + 16 * mi2 + (l >> 4) * 4 + r;
          float add = 0.f;
#pragma unroll
          for (int ei = 0; ei < 4; ++ei) add += routes_lds[ei][m] * b2v[ei];
          unsafeAtomicAdd(out + (size_t)(m0 + m) * D_MODEL + dcol, acc[mi2][h * 4 + jn][r] + add);
        }
    }
}

extern "C" void kernel_launch(void* const* d_in, const int* in_sizes, int n_in,
                              void* d_out, int out_size, void* d_ws, size_t ws_size,
                              hipStream_t stream) {
  (void)in_sizes; (void)n_in; (void)out_size; (void)ws_size;
  const float* x  = (const float*)d_in[0];
  const float* w1 = (const float*)d_in[1];
  const float* b1 = (const float*)d_in[2];
  const float* w2 = (const float*)d_in[3];
  const float* b2 = (const float*)d_in[4];
  const float* wr = (const float*)d_in[5];
  const float* br = (const float*)d_in[6];
  float* out   = (float*)d_out;
  float* route = out + (size_t)N_TOK * D_MODEL;   // output 1 lives in d_out tail

  char* ws = (char*)d_ws;
  _Float16* xb  = (_Float16*)ws;                                           // 8 MiB
  _Float16* w1t = (_Float16*)(ws + (size_t)N_TOK * D_MODEL * 2);           // +16 MiB  [E][F][D]
  _Float16* w2t = (_Float16*)(ws + (size_t)N_TOK * D_MODEL * 2
                                 + (size_t)N_EXP * D_FF * D_MODEL * 2);    // +16 MiB  [E][D][F]

  hipMemsetAsync(out, 0, (size_t)N_TOK * D_MODEL * sizeof(float), stream);
  cvt_x_kernel<<<(N_TOK * D_MODEL / 8) / 256, 256, 0, stream>>>(x, xb);
  transpose_cvt_kernel<<<dim3(D_FF / 32, D_MODEL / 32, N_EXP), 256, 0, stream>>>(w1, w1t, D_MODEL, D_FF);
  transpose_cvt_kernel<<<dim3(D_MODEL / 32, D_FF / 32, N_EXP), 256, 0, stream>>>(w2, w2t, D_FF, D_MODEL);
  router_kernel<<<N_TOK / 4, 256, 0, stream>>>(x, wr, br, route);
  moe_main_kernel<<<dim3(N_TOK / BM, 2), 512, 0, stream>>>(xb, w1t, w2t, b1, b2, route, out);
}

// Round 21
// 411.260 us; speedup vs baseline: 1.4959x; 1.0055x over previous
//
#include <hip/hip_runtime.h>
#include <math.h>

#define D_MODEL 512
#define D_FF    2048
#define N_EXP   8
#define N_TOK   8192
#define BM      64
#define BF      64

typedef _Float16 half8 __attribute__((ext_vector_type(8)));
typedef float    f32x4 __attribute__((ext_vector_type(4)));

__device__ __forceinline__ void gload_lds16(const void* g, void* lds) {
  __builtin_amdgcn_global_load_lds(
      (const __attribute__((address_space(1))) unsigned int*)g,
      (__attribute__((address_space(3))) unsigned int*)lds, 16, 0, 0);
}

// ---------------- x -> fp16 ----------------
__global__ void cvt_x_kernel(const float* __restrict__ x, _Float16* __restrict__ xb) {
  int i = blockIdx.x * blockDim.x + threadIdx.x;   // 8 elems per thread
  const float4* xp = (const float4*)x + (size_t)i * 2;
  float4 v0 = xp[0], v1 = xp[1];
  half8 o;
  o[0] = (_Float16)v0.x; o[1] = (_Float16)v0.y; o[2] = (_Float16)v0.z; o[3] = (_Float16)v0.w;
  o[4] = (_Float16)v1.x; o[5] = (_Float16)v1.y; o[6] = (_Float16)v1.z; o[7] = (_Float16)v1.w;
  ((half8*)xb)[i] = o;
}

// ---------------- [E][R][C] f32 -> [E][C][R] f16 ----------------
__global__ void transpose_cvt_kernel(const float* __restrict__ in, _Float16* __restrict__ out,
                                     int R, int C) {
  __shared__ float t[32][33];
  int e = blockIdx.z, rb = blockIdx.y, cb = blockIdx.x;
  int tx = threadIdx.x & 31, ty = threadIdx.x >> 5;
  const float* src = in + ((size_t)e * R + rb * 32) * C + cb * 32;
#pragma unroll
  for (int i = 0; i < 32; i += 8) t[ty + i][tx] = src[(size_t)(ty + i) * C + tx];
  __syncthreads();
  _Float16* dst = out + ((size_t)e * C + cb * 32) * R + rb * 32;
#pragma unroll
  for (int i = 0; i < 32; i += 8) dst[(size_t)(ty + i) * R + tx] = (_Float16)t[tx][ty + i];
}

// ---------------- router: softmax(x @ wr + br) ----------------
__global__ void router_kernel(const float* __restrict__ x, const float* __restrict__ wr,
                              const float* __restrict__ br, float* __restrict__ route) {
  int t = (blockIdx.x * blockDim.x + threadIdx.x) >> 6;   // one wave per token
  int lane = threadIdx.x & 63;
  const float4* xp = (const float4*)(x + (size_t)t * D_MODEL) + lane * 2;
  float4 xv0 = xp[0], xv1 = xp[1];
  float xv[8] = {xv0.x, xv0.y, xv0.z, xv0.w, xv1.x, xv1.y, xv1.z, xv1.w};
  float acc[8] = {0, 0, 0, 0, 0, 0, 0, 0};
  int d0 = lane * 8;
#pragma unroll
  for (int i = 0; i < 8; ++i) {
    const float4* wp = (const float4*)(wr + (size_t)(d0 + i) * N_EXP);
    float4 w0 = wp[0], w1v = wp[1];
    acc[0] += xv[i] * w0.x;  acc[1] += xv[i] * w0.y;
    acc[2] += xv[i] * w0.z;  acc[3] += xv[i] * w0.w;
    acc[4] += xv[i] * w1v.x; acc[5] += xv[i] * w1v.y;
    acc[6] += xv[i] * w1v.z; acc[7] += xv[i] * w1v.w;
  }
#pragma unroll
  for (int off = 32; off > 0; off >>= 1)
#pragma unroll
    for (int e2 = 0; e2 < 8; ++e2) acc[e2] += __shfl_xor(acc[e2], off);
  float mx = -1e30f;
#pragma unroll
  for (int e2 = 0; e2 < 8; ++e2) { acc[e2] += br[e2]; mx = fmaxf(mx, acc[e2]); }
  float s = 0.f;
#pragma unroll
  for (int e2 = 0; e2 < 8; ++e2) { acc[e2] = expf(acc[e2] - mx); s += acc[e2]; }
  float inv = 1.f / s;
  if (lane < 8) route[(size_t)t * N_EXP + lane] = acc[lane] * inv;
}

// ---------------- staging: 32KB chunk-halves, 2 gload_lds per call ----------------
// chA[kh]: w1 K-half [64f][256k], row 512B = 32 x 16B groups; LDS group g holds
//          source k-group g ^ (f & 31)  (5-bit XOR involution — ZERO conflicts).
// chB[dh]: w2 d-half [256d][64f], row 128B = 8 groups; group g holds source
//          f-group g ^ (d & 7).   (measured conflict-free)
__device__ __forceinline__ void stage_A_half(const _Float16* __restrict__ w1t, int e, int f0,
                                             int khalf, char* dst, int w, int l, int i0) {
#pragma unroll
  for (int i = i0; i < i0 + 2; ++i) {
    const int n  = i * 8 + w;                     // 0..31, 1KB per instr = 2 rows
    const int f  = 2 * n + (l >> 5);
    const int sp = (l & 31) ^ (f & 31);           // inverse of 5-bit read swizzle
    gload_lds16(w1t + ((size_t)e * D_FF + f0 + f) * D_MODEL + khalf * 256 + sp * 8,
                dst + n * 1024);
  }
}
__device__ __forceinline__ void stage_B_half(const _Float16* __restrict__ w2t, int e, int f0,
                                             int dh, char* dst, int w, int l, int i0) {
#pragma unroll
  for (int i = i0; i < i0 + 2; ++i) {
    const int n  = i * 8 + w;                     // 0..31, 1KB per instr = 8 rows
    const int d  = 8 * n + (l >> 3);
    const int sp = (l & 7) ^ (d & 7);
    gload_lds16(w2t + ((size_t)e * D_MODEL + dh * 256 + d) * D_FF + f0 + sp * 8,
                dst + n * 1024);
  }
}

// ---------------- fused MoE main: 8-phase counted-vmcnt, 5 barriers/fc ----------------
// r18 base (403us). Single change: G2 retiled m-split 1 x d-split 8 INTERLEAVED
// (wave owns 32 d-cols within EACH chB half -> no idle waves, unlike r12/r19).
// Each chB fragment now read by exactly ONE wave: b2f 16 -> 8 reads/wave/fc;
// a2 fully cached in a2c[2][4] (8 reads). Net -32 wave-reads per block-fc.
// MFMA count, stage plan, vmcnt/barriers unchanged.
__global__ __launch_bounds__(512, 2)
void moe_main_kernel(const _Float16* __restrict__ xb, const _Float16* __restrict__ w1t,
                     const _Float16* __restrict__ w2t, const float* __restrict__ b1,
                     const float* __restrict__ b2, const float* __restrict__ route,
                     float* __restrict__ out) {
  __shared__ __align__(16) unsigned char chA[2][32768];   // w1 K-halves [64f][256k]
  __shared__ __align__(16) unsigned char chB[2][32768];   // w2 d-halves [256d][64f]
  __shared__ __align__(16) unsigned char hs[BM * 128];    // 8 KB [64m][64f]
  __shared__ _Float16 b1_lds[4 * D_FF];                   // 16 KB
  __shared__ float routes_lds[4][BM];                     // 1 KB

  const int tid = threadIdx.x;
  const int l   = tid & 63;
  const int w   = tid >> 6;
  const int eb  = 4 * blockIdx.y;
  const int m0  = blockIdx.x * BM;

  const int mq  = w & 3;                   // G1 m-quarter (16 rows)
  const int fh  = w >> 2;                  // G1 f-half (32 cols)
  // G2: wave owns d-cols [w*32, w*32+32) within EACH chB half, all 64 m rows.

  // stage b1 (4 experts, f16) + routes to LDS
#pragma unroll
  for (int i = 0; i < 16; ++i) {
    int idx = i * 512 + tid;
    b1_lds[idx] = (_Float16)b1[(size_t)(eb + (idx >> 11)) * D_FF + (idx & 2047)];
  }
  if (tid < 4 * BM)
    routes_lds[tid >> 6][tid & 63] = route[(size_t)(m0 + (tid & 63)) * N_EXP + eb + (tid >> 6)];
  asm volatile("s_waitcnt lgkmcnt(0)" ::: "memory");

  // x A-fragments: rows m0 + 16*mq + (l&15), K=512 -> 16 x half8 = 64 VGPR
  half8 xfrag[16];
  {
    const _Float16* xrow = xb + (size_t)(m0 + 16 * mq + (l & 15)) * D_MODEL + (l >> 4) * 8;
#pragma unroll
    for (int ks = 0; ks < 16; ++ks)
      xfrag[ks] = *(const half8*)(xrow + ks * 32);
  }

  f32x4 acc[4][4];        // [mi2][h*2+jn] — AGPR-resident (64 AGPR)
#pragma unroll
  for (int a = 0; a < 4; ++a)
#pragma unroll
    for (int b = 0; b < 4; ++b) acc[a][b] = (f32x4){0.f, 0.f, 0.f, 0.f};

  // prologue: Ah0, Ah1, Bh0 of (eb, fc0); Bh1(fc0) staged in P1-2.
  stage_A_half(w1t, eb, 0, 0, (char*)chA[0], w, l, 0);
  stage_A_half(w1t, eb, 0, 0, (char*)chA[0], w, l, 2);
  stage_A_half(w1t, eb, 0, 1, (char*)chA[1], w, l, 0);
  stage_A_half(w1t, eb, 0, 1, (char*)chA[1], w, l, 2);
  stage_B_half(w2t, eb, 0, 0, (char*)chB[0], w, l, 0);
  stage_B_half(w2t, eb, 0, 0, (char*)chB[0], w, l, 2);
  asm volatile("s_waitcnt vmcnt(8)" ::: "memory");   // Ah0 landed
  __builtin_amdgcn_s_barrier();

#pragma unroll 1
  for (int ei = 0; ei < 4; ++ei) {
    const int e = eb + ei;
#pragma unroll 1
    for (int fc = 0; fc < 32; ++fc) {
      const int f0 = fc * BF;
      int f0N = f0 + BF, eN = e;
      if (f0N == D_FF) { f0N = 0; eN = (ei < 3) ? e + 1 : eb; }   // tail wrap (harmless)

      float b1v[2];
#pragma unroll
      for (int j = 0; j < 2; ++j)
        b1v[j] = (float)b1_lds[ei * D_FF + f0 + 32 * fh + 16 * j + (l & 15)];

      f32x4 hacc[2];
      hacc[0] = (f32x4){0.f, 0.f, 0.f, 0.f};
      hacc[1] = (f32x4){0.f, 0.f, 0.f, 0.f};

      // ======== P1..P4: GEMM1 (kq = K-quarter), 8 MFMA each ========
#pragma unroll
      for (int kq = 0; kq < 4; ++kq) {
        const unsigned char* cA = chA[kq >> 1];
        const int q = kq & 1;
        half8 bfr[4][2];
#pragma unroll
        for (int t = 0; t < 4; ++t)
#pragma unroll
          for (int j = 0; j < 2; ++j) {
            const int f  = 32 * fh + 16 * j + (l & 15);
            const int g  = q * 16 + t * 4 + (l >> 4);
            const int sw = (g ^ f) & 31;          // 5-bit XOR: conflict-free
            bfr[t][j] = *(const half8*)(cA + f * 512 + sw * 16);
          }
        if      (kq == 0) stage_B_half(w2t, e,  f0,  1, (char*)chB[1], w, l, 0);
        else if (kq == 1) stage_B_half(w2t, e,  f0,  1, (char*)chB[1], w, l, 2);
        else if (kq == 2) stage_A_half(w1t, eN, f0N, 0, (char*)chA[0], w, l, 0);
        else              stage_A_half(w1t, eN, f0N, 0, (char*)chA[0], w, l, 2);
        if (kq & 1) {
          asm volatile("s_waitcnt vmcnt(8)" ::: "memory");
          __builtin_amdgcn_s_barrier();            // P2/P4 leading: chunk visibility
        }
        asm volatile("s_waitcnt lgkmcnt(0)" ::: "memory");
        __builtin_amdgcn_s_setprio(1);
#pragma unroll
        for (int t = 0; t < 4; ++t) {
          hacc[0] = __builtin_amdgcn_mfma_f32_16x16x32_f16(xfrag[kq * 4 + t], bfr[t][0], hacc[0], 0, 0, 0);
          hacc[1] = __builtin_amdgcn_mfma_f32_16x16x32_f16(xfrag[kq * 4 + t], bfr[t][1], hacc[1], 0, 0, 0);
        }
        __builtin_amdgcn_s_setprio(0);
        if (kq == 3) {
          // bias + tanh-gelu + route-scale -> hs (16 rows x 32 cols per wave)
#pragma unroll
          for (int j = 0; j < 2; ++j) {
#pragma unroll
            for (int r = 0; r < 4; ++r) {
              const int m      = 16 * mq + (l >> 4) * 4 + r;
              const int flocal = 32 * fh + 16 * j + (l & 15);
              float v  = hacc[j][r] + b1v[j];
              float u  = v * (1.5957691f + 0.0713548f * v * v);
              float E  = __expf(u);
              float gl = v * E / (E + 1.0f);
              gl *= routes_lds[ei][m];
              const int sh = (flocal >> 3) ^ ((m ^ (m >> 1)) & 7);
              *(_Float16*)(hs + m * 128 + sh * 16 + (flocal & 7) * 2) = (_Float16)gl;
            }
          }
          asm volatile("s_waitcnt lgkmcnt(0)" ::: "memory");
          __builtin_amdgcn_s_barrier();            // P4 trailing: hs publish
        }
      }

      // ======== P5..P8: GEMM2 (c: h = c>>1 d-half, kh = c&1), 8 MFMA each ========
      half8 a2c[2][4];   // [kh][mi2] — all 64 m rows, loaded at c=0,1; reused at c=2,3
#pragma unroll
      for (int c = 0; c < 4; ++c) {
        const int h  = c >> 1;
        const int kh = c & 1;
        if (h == 0) {
#pragma unroll
          for (int mi2 = 0; mi2 < 4; ++mi2) {
            const int mr = 16 * mi2 + (l & 15);
            const int sh = (kh * 4 + (l >> 4)) ^ ((mr ^ (mr >> 1)) & 7);
            a2c[kh][mi2] = *(const half8*)(hs + mr * 128 + sh * 16);
          }
        }
        half8 b2f[2];
#pragma unroll
        for (int jn = 0; jn < 2; ++jn) {
          const int row = w * 32 + jn * 16 + (l & 15);   // wave-private 32 d-cols
          const int sw  = (kh * 4 + (l >> 4)) ^ (row & 7);
          b2f[jn] = *(const half8*)(chB[h] + row * 128 + sw * 16);
        }
        if      (c == 0) stage_A_half(w1t, eN, f0N, 1, (char*)chA[1], w, l, 0);
        else if (c == 1) stage_A_half(w1t, eN, f0N, 1, (char*)chA[1], w, l, 2);
        else if (c == 2) stage_B_half(w2t, eN, f0N, 0, (char*)chB[0], w, l, 0);
        else             stage_B_half(w2t, eN, f0N, 0, (char*)chB[0], w, l, 2);
        if (c & 1) {
          asm volatile("s_waitcnt vmcnt(8)" ::: "memory");
          __builtin_amdgcn_s_barrier();            // P6/P8 leading: chunk visibility
        }
        asm volatile("s_waitcnt lgkmcnt(0)" ::: "memory");
        __builtin_amdgcn_s_setprio(1);
#pragma unroll
        for (int jn = 0; jn < 2; ++jn)
#pragma unroll
          for (int mi2 = 0; mi2 < 4; ++mi2)
            acc[mi2][h * 2 + jn] = __builtin_amdgcn_mfma_f32_16x16x32_f16(a2c[kh][mi2], b2f[jn], acc[mi2][h * 2 + jn], 0, 0, 0);
        __builtin_amdgcn_s_setprio(0);
      }
    }
  }

  asm volatile("s_waitcnt vmcnt(0)" ::: "memory");   // drain tail prefetches

  // ---- epilogue: += sum_e route*b2, then 2-way atomic accumulate ----
#pragma unroll
  for (int h = 0; h < 2; ++h)
#pragma unroll
    for (int jn = 0; jn < 2; ++jn) {
      const int dcol = h * 256 + w * 32 + jn * 16 + (l & 15);
      float b2v[4];
#pragma unroll
      for (int ei = 0; ei < 4; ++ei) b2v[ei] = b2[(size_t)(eb + ei) * D_MODEL + dcol];
#pragma unroll
      for (int mi2 = 0; mi2 < 4; ++mi2)
#pragma unroll
        for (int r = 0; r < 4; ++r) {
          const int m = 16 * mi2 + (l >> 4) * 4 + r;
          float add = 0.f;
#pragma unroll
          for (int ei = 0; ei < 4; ++ei) add += routes_lds[ei][m] * b2v[ei];
          unsafeAtomicAdd(out + (size_t)(m0 + m) * D_MODEL + dcol, acc[mi2][h * 2 + jn][r] + add);
        }
    }
}

extern "C" void kernel_launch(void* const* d_in, const int* in_sizes, int n_in,
                              void* d_out, int out_size, void* d_ws, size_t ws_size,
                              hipStream_t stream) {
  (void)in_sizes; (void)n_in; (void)out_size; (void)ws_size;
  const float* x  = (const float*)d_in[0];
  const float* w1 = (const float*)d_in[1];
  const float* b1 = (const float*)d_in[2];
  const float* w2 = (const float*)d_in[3];
  const float* b2 = (const float*)d_in[4];
  const float* wr = (const float*)d_in[5];
  const float* br = (const float*)d_in[6];
  float* out   = (float*)d_out;
  float* route = out + (size_t)N_TOK * D_MODEL;   // output 1 lives in d_out tail

  char* ws = (char*)d_ws;
  _Float16* xb  = (_Float16*)ws;                                           // 8 MiB
  _Float16* w1t = (_Float16*)(ws + (size_t)N_TOK * D_MODEL * 2);           // +16 MiB  [E][F][D]
  _Float16* w2t = (_Float16*)(ws + (size_t)N_TOK * D_MODEL * 2
                                 + (size_t)N_EXP * D_FF * D_MODEL * 2);    // +16 MiB  [E][D][F]

  hipMemsetAsync(out, 0, (size_t)N_TOK * D_MODEL * sizeof(float), stream);
  cvt_x_kernel<<<(N_TOK * D_MODEL / 8) / 256, 256, 0, stream>>>(x, xb);
  transpose_cvt_kernel<<<dim3(D_FF / 32, D_MODEL / 32, N_EXP), 256, 0, stream>>>(w1, w1t, D_MODEL, D_FF);
  transpose_cvt_kernel<<<dim3(D_MODEL / 32, D_FF / 32, N_EXP), 256, 0, stream>>>(w2, w2t, D_FF, D_MODEL);
  router_kernel<<<N_TOK / 4, 256, 0, stream>>>(x, wr, br, route);
  moe_main_kernel<<<dim3(N_TOK / BM, 2), 512, 0, stream>>>(xb, w1t, w2t, b1, b2, route, out);
}

// Round 22
// 386.272 us; speedup vs baseline: 1.5927x; 1.0647x over previous
//
#include <hip/hip_runtime.h>
#include <math.h>

#define D_MODEL 512
#define D_FF    2048
#define N_EXP   8
#define N_TOK   8192
#define BM      64
#define BF      64

typedef _Float16 half8 __attribute__((ext_vector_type(8)));
typedef float    f32x4 __attribute__((ext_vector_type(4)));

__device__ __forceinline__ void gload_lds16(const void* g, void* lds) {
  __builtin_amdgcn_global_load_lds(
      (const __attribute__((address_space(1))) unsigned int*)g,
      (__attribute__((address_space(3))) unsigned int*)lds, 16, 0, 0);
}

// ---------------- x -> fp16 ----------------
__global__ void cvt_x_kernel(const float* __restrict__ x, _Float16* __restrict__ xb) {
  int i = blockIdx.x * blockDim.x + threadIdx.x;   // 8 elems per thread
  const float4* xp = (const float4*)x + (size_t)i * 2;
  float4 v0 = xp[0], v1 = xp[1];
  half8 o;
  o[0] = (_Float16)v0.x; o[1] = (_Float16)v0.y; o[2] = (_Float16)v0.z; o[3] = (_Float16)v0.w;
  o[4] = (_Float16)v1.x; o[5] = (_Float16)v1.y; o[6] = (_Float16)v1.z; o[7] = (_Float16)v1.w;
  ((half8*)xb)[i] = o;
}

// ---------------- [E][R][C] f32 -> [E][C][R] f16 ----------------
__global__ void transpose_cvt_kernel(const float* __restrict__ in, _Float16* __restrict__ out,
                                     int R, int C) {
  __shared__ float t[32][33];
  int e = blockIdx.z, rb = blockIdx.y, cb = blockIdx.x;
  int tx = threadIdx.x & 31, ty = threadIdx.x >> 5;
  const float* src = in + ((size_t)e * R + rb * 32) * C + cb * 32;
#pragma unroll
  for (int i = 0; i < 32; i += 8) t[ty + i][tx] = src[(size_t)(ty + i) * C + tx];
  __syncthreads();
  _Float16* dst = out + ((size_t)e * C + cb * 32) * R + rb * 32;
#pragma unroll
  for (int i = 0; i < 32; i += 8) dst[(size_t)(ty + i) * R + tx] = (_Float16)t[tx][ty + i];
}

// ---------------- router: softmax(x @ wr + br) ----------------
__global__ void router_kernel(const float* __restrict__ x, const float* __restrict__ wr,
                              const float* __restrict__ br, float* __restrict__ route) {
  int t = (blockIdx.x * blockDim.x + threadIdx.x) >> 6;   // one wave per token
  int lane = threadIdx.x & 63;
  const float4* xp = (const float4*)(x + (size_t)t * D_MODEL) + lane * 2;
  float4 xv0 = xp[0], xv1 = xp[1];
  float xv[8] = {xv0.x, xv0.y, xv0.z, xv0.w, xv1.x, xv1.y, xv1.z, xv1.w};
  float acc[8] = {0, 0, 0, 0, 0, 0, 0, 0};
  int d0 = lane * 8;
#pragma unroll
  for (int i = 0; i < 8; ++i) {
    const float4* wp = (const float4*)(wr + (size_t)(d0 + i) * N_EXP);
    float4 w0 = wp[0], w1v = wp[1];
    acc[0] += xv[i] * w0.x;  acc[1] += xv[i] * w0.y;
    acc[2] += xv[i] * w0.z;  acc[3] += xv[i] * w0.w;
    acc[4] += xv[i] * w1v.x; acc[5] += xv[i] * w1v.y;
    acc[6] += xv[i] * w1v.z; acc[7] += xv[i] * w1v.w;
  }
#pragma unroll
  for (int off = 32; off > 0; off >>= 1)
#pragma unroll
    for (int e2 = 0; e2 < 8; ++e2) acc[e2] += __shfl_xor(acc[e2], off);
  float mx = -1e30f;
#pragma unroll
  for (int e2 = 0; e2 < 8; ++e2) { acc[e2] += br[e2]; mx = fmaxf(mx, acc[e2]); }
  float s = 0.f;
#pragma unroll
  for (int e2 = 0; e2 < 8; ++e2) { acc[e2] = expf(acc[e2] - mx); s += acc[e2]; }
  float inv = 1.f / s;
  if (lane < 8) route[(size_t)t * N_EXP + lane] = acc[lane] * inv;
}

// ---------------- staging: 32KB chunk-halves, 2 gload_lds per call ----------------
// chA[kh]: w1 K-half [64f][256k], row 512B = 32 x 16B groups; LDS group g holds
//          source k-group g ^ (f & 31)  (5-bit XOR involution — ZERO conflicts).
// chB[dh]: w2 d-half [256d][64f], row 128B = 8 groups; group g holds source
//          f-group g ^ (d & 7).   (measured conflict-free)
__device__ __forceinline__ void stage_A_half(const _Float16* __restrict__ w1t, int e, int f0,
                                             int khalf, char* dst, int w, int l, int i0) {
#pragma unroll
  for (int i = i0; i < i0 + 2; ++i) {
    const int n  = i * 8 + w;                     // 0..31, 1KB per instr = 2 rows
    const int f  = 2 * n + (l >> 5);
    const int sp = (l & 31) ^ (f & 31);           // inverse of 5-bit read swizzle
    gload_lds16(w1t + ((size_t)e * D_FF + f0 + f) * D_MODEL + khalf * 256 + sp * 8,
                dst + n * 1024);
  }
}
__device__ __forceinline__ void stage_B_half(const _Float16* __restrict__ w2t, int e, int f0,
                                             int dh, char* dst, int w, int l, int i0) {
#pragma unroll
  for (int i = i0; i < i0 + 2; ++i) {
    const int n  = i * 8 + w;                     // 0..31, 1KB per instr = 8 rows
    const int d  = 8 * n + (l >> 3);
    const int sp = (l & 7) ^ (d & 7);
    gload_lds16(w2t + ((size_t)e * D_MODEL + dh * 256 + d) * D_FF + f0 + sp * 8,
                dst + n * 1024);
  }
}

// ---------------- fused MoE main: 8-phase counted-vmcnt, 5 barriers/fc ----------------
// r21 base (400us: G2 d-split 8 interleaved, a2 fully cached). Single change:
// gelu's IEEE division replaced with v_rcp_f32 (~1 ulp; values bounded, error
// budget 1.27e-2) — cuts ~6 VALU ops per h value (div_scale/fmas/fixup chain).
__global__ __launch_bounds__(512, 2)
void moe_main_kernel(const _Float16* __restrict__ xb, const _Float16* __restrict__ w1t,
                     const _Float16* __restrict__ w2t, const float* __restrict__ b1,
                     const float* __restrict__ b2, const float* __restrict__ route,
                     float* __restrict__ out) {
  __shared__ __align__(16) unsigned char chA[2][32768];   // w1 K-halves [64f][256k]
  __shared__ __align__(16) unsigned char chB[2][32768];   // w2 d-halves [256d][64f]
  __shared__ __align__(16) unsigned char hs[BM * 128];    // 8 KB [64m][64f]
  __shared__ _Float16 b1_lds[4 * D_FF];                   // 16 KB
  __shared__ float routes_lds[4][BM];                     // 1 KB

  const int tid = threadIdx.x;
  const int l   = tid & 63;
  const int w   = tid >> 6;
  const int eb  = 4 * blockIdx.y;
  const int m0  = blockIdx.x * BM;

  const int mq  = w & 3;                   // G1 m-quarter (16 rows)
  const int fh  = w >> 2;                  // G1 f-half (32 cols)
  // G2: wave owns d-cols [w*32, w*32+32) within EACH chB half, all 64 m rows.

  // stage b1 (4 experts, f16) + routes to LDS
#pragma unroll
  for (int i = 0; i < 16; ++i) {
    int idx = i * 512 + tid;
    b1_lds[idx] = (_Float16)b1[(size_t)(eb + (idx >> 11)) * D_FF + (idx & 2047)];
  }
  if (tid < 4 * BM)
    routes_lds[tid >> 6][tid & 63] = route[(size_t)(m0 + (tid & 63)) * N_EXP + eb + (tid >> 6)];
  asm volatile("s_waitcnt lgkmcnt(0)" ::: "memory");

  // x A-fragments: rows m0 + 16*mq + (l&15), K=512 -> 16 x half8 = 64 VGPR
  half8 xfrag[16];
  {
    const _Float16* xrow = xb + (size_t)(m0 + 16 * mq + (l & 15)) * D_MODEL + (l >> 4) * 8;
#pragma unroll
    for (int ks = 0; ks < 16; ++ks)
      xfrag[ks] = *(const half8*)(xrow + ks * 32);
  }

  f32x4 acc[4][4];        // [mi2][h*2+jn] — AGPR-resident (64 AGPR)
#pragma unroll
  for (int a = 0; a < 4; ++a)
#pragma unroll
    for (int b = 0; b < 4; ++b) acc[a][b] = (f32x4){0.f, 0.f, 0.f, 0.f};

  // prologue: Ah0, Ah1, Bh0 of (eb, fc0); Bh1(fc0) staged in P1-2.
  stage_A_half(w1t, eb, 0, 0, (char*)chA[0], w, l, 0);
  stage_A_half(w1t, eb, 0, 0, (char*)chA[0], w, l, 2);
  stage_A_half(w1t, eb, 0, 1, (char*)chA[1], w, l, 0);
  stage_A_half(w1t, eb, 0, 1, (char*)chA[1], w, l, 2);
  stage_B_half(w2t, eb, 0, 0, (char*)chB[0], w, l, 0);
  stage_B_half(w2t, eb, 0, 0, (char*)chB[0], w, l, 2);
  asm volatile("s_waitcnt vmcnt(8)" ::: "memory");   // Ah0 landed
  __builtin_amdgcn_s_barrier();

#pragma unroll 1
  for (int ei = 0; ei < 4; ++ei) {
    const int e = eb + ei;
#pragma unroll 1
    for (int fc = 0; fc < 32; ++fc) {
      const int f0 = fc * BF;
      int f0N = f0 + BF, eN = e;
      if (f0N == D_FF) { f0N = 0; eN = (ei < 3) ? e + 1 : eb; }   // tail wrap (harmless)

      float b1v[2];
#pragma unroll
      for (int j = 0; j < 2; ++j)
        b1v[j] = (float)b1_lds[ei * D_FF + f0 + 32 * fh + 16 * j + (l & 15)];

      f32x4 hacc[2];
      hacc[0] = (f32x4){0.f, 0.f, 0.f, 0.f};
      hacc[1] = (f32x4){0.f, 0.f, 0.f, 0.f};

      // ======== P1..P4: GEMM1 (kq = K-quarter), 8 MFMA each ========
#pragma unroll
      for (int kq = 0; kq < 4; ++kq) {
        const unsigned char* cA = chA[kq >> 1];
        const int q = kq & 1;
        half8 bfr[4][2];
#pragma unroll
        for (int t = 0; t < 4; ++t)
#pragma unroll
          for (int j = 0; j < 2; ++j) {
            const int f  = 32 * fh + 16 * j + (l & 15);
            const int g  = q * 16 + t * 4 + (l >> 4);
            const int sw = (g ^ f) & 31;          // 5-bit XOR: conflict-free
            bfr[t][j] = *(const half8*)(cA + f * 512 + sw * 16);
          }
        if      (kq == 0) stage_B_half(w2t, e,  f0,  1, (char*)chB[1], w, l, 0);
        else if (kq == 1) stage_B_half(w2t, e,  f0,  1, (char*)chB[1], w, l, 2);
        else if (kq == 2) stage_A_half(w1t, eN, f0N, 0, (char*)chA[0], w, l, 0);
        else              stage_A_half(w1t, eN, f0N, 0, (char*)chA[0], w, l, 2);
        if (kq & 1) {
          asm volatile("s_waitcnt vmcnt(8)" ::: "memory");
          __builtin_amdgcn_s_barrier();            // P2/P4 leading: chunk visibility
        }
        asm volatile("s_waitcnt lgkmcnt(0)" ::: "memory");
        __builtin_amdgcn_s_setprio(1);
#pragma unroll
        for (int t = 0; t < 4; ++t) {
          hacc[0] = __builtin_amdgcn_mfma_f32_16x16x32_f16(xfrag[kq * 4 + t], bfr[t][0], hacc[0], 0, 0, 0);
          hacc[1] = __builtin_amdgcn_mfma_f32_16x16x32_f16(xfrag[kq * 4 + t], bfr[t][1], hacc[1], 0, 0, 0);
        }
        __builtin_amdgcn_s_setprio(0);
        if (kq == 3) {
          // bias + tanh-gelu + route-scale -> hs (16 rows x 32 cols per wave)
#pragma unroll
          for (int j = 0; j < 2; ++j) {
#pragma unroll
            for (int r = 0; r < 4; ++r) {
              const int m      = 16 * mq + (l >> 4) * 4 + r;
              const int flocal = 32 * fh + 16 * j + (l & 15);
              float v  = hacc[j][r] + b1v[j];
              float u  = v * (1.5957691f + 0.0713548f * v * v);
              float E  = __expf(u);
              float gl = v * E * __builtin_amdgcn_rcpf(E + 1.0f);
              gl *= routes_lds[ei][m];
              const int sh = (flocal >> 3) ^ ((m ^ (m >> 1)) & 7);
              *(_Float16*)(hs + m * 128 + sh * 16 + (flocal & 7) * 2) = (_Float16)gl;
            }
          }
          asm volatile("s_waitcnt lgkmcnt(0)" ::: "memory");
          __builtin_amdgcn_s_barrier();            // P4 trailing: hs publish
        }
      }

      // ======== P5..P8: GEMM2 (c: h = c>>1 d-half, kh = c&1), 8 MFMA each ========
      half8 a2c[2][4];   // [kh][mi2] — all 64 m rows, loaded at c=0,1; reused at c=2,3
#pragma unroll
      for (int c = 0; c < 4; ++c) {
        const int h  = c >> 1;
        const int kh = c & 1;
        if (h == 0) {
#pragma unroll
          for (int mi2 = 0; mi2 < 4; ++mi2) {
            const int mr = 16 * mi2 + (l & 15);
            const int sh = (kh * 4 + (l >> 4)) ^ ((mr ^ (mr >> 1)) & 7);
            a2c[kh][mi2] = *(const half8*)(hs + mr * 128 + sh * 16);
          }
        }
        half8 b2f[2];
#pragma unroll
        for (int jn = 0; jn < 2; ++jn) {
          const int row = w * 32 + jn * 16 + (l & 15);   // wave-private 32 d-cols
          const int sw  = (kh * 4 + (l >> 4)) ^ (row & 7);
          b2f[jn] = *(const half8*)(chB[h] + row * 128 + sw * 16);
        }
        if      (c == 0) stage_A_half(w1t, eN, f0N, 1, (char*)chA[1], w, l, 0);
        else if (c == 1) stage_A_half(w1t, eN, f0N, 1, (char*)chA[1], w, l, 2);
        else if (c == 2) stage_B_half(w2t, eN, f0N, 0, (char*)chB[0], w, l, 0);
        else             stage_B_half(w2t, eN, f0N, 0, (char*)chB[0], w, l, 2);
        if (c & 1) {
          asm volatile("s_waitcnt vmcnt(8)" ::: "memory");
          __builtin_amdgcn_s_barrier();            // P6/P8 leading: chunk visibility
        }
        asm volatile("s_waitcnt lgkmcnt(0)" ::: "memory");
        __builtin_amdgcn_s_setprio(1);
#pragma unroll
        for (int jn = 0; jn < 2; ++jn)
#pragma unroll
          for (int mi2 = 0; mi2 < 4; ++mi2)
            acc[mi2][h * 2 + jn] = __builtin_amdgcn_mfma_f32_16x16x32_f16(a2c[kh][mi2], b2f[jn], acc[mi2][h * 2 + jn], 0, 0, 0);
        __builtin_amdgcn_s_setprio(0);
      }
    }
  }

  asm volatile("s_waitcnt vmcnt(0)" ::: "memory");   // drain tail prefetches

  // ---- epilogue: += sum_e route*b2, then 2-way atomic accumulate ----
#pragma unroll
  for (int h = 0; h < 2; ++h)
#pragma unroll
    for (int jn = 0; jn < 2; ++jn) {
      const int dcol = h * 256 + w * 32 + jn * 16 + (l & 15);
      float b2v[4];
#pragma unroll
      for (int ei = 0; ei < 4; ++ei) b2v[ei] = b2[(size_t)(eb + ei) * D_MODEL + dcol];
#pragma unroll
      for (int mi2 = 0; mi2 < 4; ++mi2)
#pragma unroll
        for (int r = 0; r < 4; ++r) {
          const int m = 16 * mi2 + (l >> 4) * 4 + r;
          float add = 0.f;
#pragma unroll
          for (int ei = 0; ei < 4; ++ei) add += routes_lds[ei][m] * b2v[ei];
          unsafeAtomicAdd(out + (size_t)(m0 + m) * D_MODEL + dcol, acc[mi2][h * 2 + jn][r] + add);
        }
    }
}

extern "C" void kernel_launch(void* const* d_in, const int* in_sizes, int n_in,
                              void* d_out, int out_size, void* d_ws, size_t ws_size,
                              hipStream_t stream) {
  (void)in_sizes; (void)n_in; (void)out_size; (void)ws_size;
  const float* x  = (const float*)d_in[0];
  const float* w1 = (const float*)d_in[1];
  const float* b1 = (const float*)d_in[2];
  const float* w2 = (const float*)d_in[3];
  const float* b2 = (const float*)d_in[4];
  const float* wr = (const float*)d_in[5];
  const float* br = (const float*)d_in[6];
  float* out   = (float*)d_out;
  float* route = out + (size_t)N_TOK * D_MODEL;   // output 1 lives in d_out tail

  char* ws = (char*)d_ws;
  _Float16* xb  = (_Float16*)ws;                                           // 8 MiB
  _Float16* w1t = (_Float16*)(ws + (size_t)N_TOK * D_MODEL * 2);           // +16 MiB  [E][F][D]
  _Float16* w2t = (_Float16*)(ws + (size_t)N_TOK * D_MODEL * 2
                                 + (size_t)N_EXP * D_FF * D_MODEL * 2);    // +16 MiB  [E][D][F]

  hipMemsetAsync(out, 0, (size_t)N_TOK * D_MODEL * sizeof(float), stream);
  cvt_x_kernel<<<(N_TOK * D_MODEL / 8) / 256, 256, 0, stream>>>(x, xb);
  transpose_cvt_kernel<<<dim3(D_FF / 32, D_MODEL / 32, N_EXP), 256, 0, stream>>>(w1, w1t, D_MODEL, D_FF);
  transpose_cvt_kernel<<<dim3(D_MODEL / 32, D_FF / 32, N_EXP), 256, 0, stream>>>(w2, w2t, D_FF, D_MODEL);
  router_kernel<<<N_TOK / 4, 256, 0, stream>>>(x, wr, br, route);
  moe_main_kernel<<<dim3(N_TOK / BM, 2), 512, 0, stream>>>(xb, w1t, w2t, b1, b2, route, out);
}